// Round 7
// baseline (1176.918 us; speedup 1.0000x reference)
//
#include <hip/hip_runtime.h>
#include <hip/hip_bf16.h>

typedef __attribute__((ext_vector_type(8))) short bf16x8;
typedef __attribute__((ext_vector_type(4))) float f32x4;

#define EPSV 1e-5f
#define NN 50000
#define NE 800000
#define NG 64
#define MFMA16(a, b, c) __builtin_amdgcn_mfma_f32_16x16x32_bf16(a, b, c, 0, 0, 0)

__device__ __forceinline__ unsigned short f2bf(float f) {
  union { float f; unsigned u; } v; v.f = f;
  unsigned r = v.u + 0x7FFFu + ((v.u >> 16) & 1u);
  return (unsigned short)(r >> 16);
}

// ---------------- conversion kernels ----------------

__global__ __launch_bounds__(256) void cvt_vec_kernel(
    const float* __restrict__ x, const float* __restrict__ e,
    unsigned short* __restrict__ xb, unsigned short* __restrict__ eb) {
  const int NX4 = (NN * 128) / 4;
  const int NE4 = (NE * 32) / 4;
  const int total = NX4 + NE4;
  for (int idx = blockIdx.x * 256 + threadIdx.x; idx < total;
       idx += gridDim.x * 256) {
    float4 v = (idx < NX4) ? ((const float4*)x)[idx]
                           : ((const float4*)e)[idx - NX4];
    ushort4 o;
    o.x = f2bf(v.x); o.y = f2bf(v.y); o.z = f2bf(v.z); o.w = f2bf(v.w);
    if (idx < NX4) ((ushort4*)xb)[idx] = o;
    else           ((ushort4*)eb)[idx - NX4] = o;
  }
}

__global__ __launch_bounds__(256) void cvt_small_kernel(
    const float* __restrict__ u,
    const float* __restrict__ eW1, const float* __restrict__ eW2,
    const float* __restrict__ nW1, const float* __restrict__ nW2,
    unsigned short* __restrict__ ub,
    unsigned short* __restrict__ eW1T, unsigned short* __restrict__ eW2T,
    unsigned short* __restrict__ nW1T, unsigned short* __restrict__ nW2T) {
  int i = blockIdx.x * 256 + threadIdx.x;
  const int R0 = NG * 32;
  const int R1 = R0 + 128 * 320;
  const int R2 = R1 + 128 * 128;
  const int R3 = R2 + 128 * 320;
  const int R4 = R3 + 128 * 128;
  if (i < R0) {
    ub[i] = f2bf(u[i]);
  } else if (i < R1) {
    int j = i - R0; int n = j / 320, k = j % 320;
    eW1T[j] = f2bf(eW1[k * 128 + n]);
  } else if (i < R2) {
    int j = i - R1; int n = j / 128, k = j % 128;
    eW2T[j] = f2bf(eW2[k * 128 + n]);
  } else if (i < R3) {
    int j = i - R2; int n = j / 320, k = j % 320;
    nW1T[j] = (k < 288) ? f2bf(nW1[k * 128 + n]) : (unsigned short)0;
  } else if (i < R4) {
    int j = i - R3; int n = j / 128, k = j % 128;
    nW2T[j] = f2bf(nW2[k * 128 + n]);
  }
}

// ---------------- CSR construction (receiver + sender) ----------------

__global__ __launch_bounds__(256) void pre_kernel(
    const int* __restrict__ rowIdx, const int* __restrict__ colIdx,
    int* __restrict__ cnt_r, int* __restrict__ cnt_s) {
  int i = blockIdx.x * 256 + threadIdx.x;
  if (i < NE) {
    atomicAdd(&cnt_r[colIdx[i]], 1);
    atomicAdd(&cnt_s[rowIdx[i]], 1);
  }
}

__global__ __launch_bounds__(1024) void scan_kernel(
    const int* __restrict__ cnt, int* __restrict__ offs,
    int* __restrict__ cur) {
  __shared__ int sums[1024];
  const int t = threadIdx.x;
  const int base = t * 49;
  int s = 0;
  for (int j = 0; j < 49; ++j) {
    int idx = base + j;
    if (idx < NN) s += cnt[idx];
  }
  sums[t] = s;
  __syncthreads();
  for (int off = 1; off < 1024; off <<= 1) {
    int add = (t >= off) ? sums[t - off] : 0;
    __syncthreads();
    sums[t] += add;
    __syncthreads();
  }
  int run = (t == 0) ? 0 : sums[t - 1];
  for (int j = 0; j < 49; ++j) {
    int idx = base + j;
    if (idx < NN) {
      offs[idx] = run; cur[idx] = run;
      run += cnt[idx];
    }
  }
}

__global__ __launch_bounds__(256) void fill_kernel(
    const int* __restrict__ colIdx, int* __restrict__ cur,
    int* __restrict__ eidlist) {
  int i = blockIdx.x * 256 + threadIdx.x;
  if (i < NE) {
    int p = atomicAdd(&cur[colIdx[i]], 1);
    eidlist[p] = i;
  }
}

__global__ __launch_bounds__(256) void fill2_kernel(
    const int* __restrict__ rowIdx, const int* __restrict__ batch,
    int* __restrict__ cur_s, int* __restrict__ eidlist_s,
    int* __restrict__ gs) {
  int i = blockIdx.x * 256 + threadIdx.x;
  if (i < NE) {
    const int r = rowIdx[i];
    const int p = atomicAdd(&cur_s[r], 1);
    eidlist_s[p] = i;
    gs[p] = batch[r];
  }
}

// ---------------- fused MLP kernel (edge MODE=0 / node MODE=1) ----------------
// 64 rows/block, 512 threads = 8 waves as 2M x 4N: wave (wm,wn) computes rows
// wm*32..+31, cols wn*32..+31. All weights in REGISTERS (loaded once/block
// from L2-hot W1T/W2T) -> no B staging, 3-5 barriers/tile (was 14).
// LayerNorm via cross-wave LDS partials ps/pss[64][4].
template <int MODE>
__global__ __launch_bounds__(512, 3) void mlp_kernel(
    const unsigned short* __restrict__ ebuf,
    const unsigned short* __restrict__ xb,
    const unsigned short* __restrict__ ub,
    const float* __restrict__ aggsrc,
    const int* __restrict__ rowIdx, const int* __restrict__ colIdx,
    const int* __restrict__ batch,
    const int* __restrict__ offs, const int* __restrict__ cnt,
    const int* __restrict__ eidlist,
    const unsigned short* __restrict__ W1T,   // [128][320] bf16
    const unsigned short* __restrict__ W2T,   // [128][128] bf16
    const float* __restrict__ b1, const float* __restrict__ b2,
    const float* __restrict__ gam, const float* __restrict__ bet,
    float* __restrict__ out, float* __restrict__ aggout, int nRows) {
  // MODE0: Asm[64][328]=41984 + separate Hsm[64][136]=17408 (no alias).
  // MODE1: U=50176; Hsm aliases U[0..17408), bins f32[8192] at U+17408
  //        (both alias Asm, dead after GEMM1; extra barrier protects).
  constexpr int USZ = (MODE == 1) ? 50176 : (41984 + 17408);
  __shared__ __align__(16) char U[USZ];
  __shared__ float ps[64][4], pss[64][4];
  __shared__ float cb1[128], cb2[128], cg[128], cbt[128];
  unsigned short (*Asm)[328] = (unsigned short(*)[328])U;
  unsigned short (*Hsm)[136] =
      (unsigned short(*)[136])(MODE == 1 ? U : U + 41984);
  float* bins = (float*)(U + 17408);

  const int tid = threadIdx.x;
  if (tid < 128) {
    cb1[tid] = b1[tid]; cb2[tid] = b2[tid];
    cg[tid] = gam[tid]; cbt[tid] = bet[tid];
  }

  const int wave = tid >> 6;
  const int wm = wave >> 2;        // 0..1 : row group
  const int wn = wave & 3;         // 0..3 : col group
  const int lane = tid & 63;
  const int l15 = lane & 15, lg = lane >> 4;

  // ---- B1 registers: wave's 2 col-blocks, full K=320 (20 frags, 80 VGPR) ----
  bf16x8 B1[2][5][2];
  {
    const unsigned short* w1b = W1T + (size_t)(wn * 32 + l15) * 320 + lg * 8;
#pragma unroll
    for (int ni = 0; ni < 2; ++ni)
#pragma unroll
      for (int kc = 0; kc < 5; ++kc)
#pragma unroll
        for (int h = 0; h < 2; ++h)
          B1[ni][kc][h] =
              *(const bf16x8*)(w1b + ni * (16 * 320) + kc * 64 + h * 32);
  }

  // ---- stage A tile: 8 threads per row ----
  {
    const int r = tid >> 3, q = tid & 7;
    const int grow = blockIdx.x * 64 + r;
    if (MODE == 0) {
      const int rcv = colIdx[grow];
      const int snd = rowIdx[grow];
      const int g = batch[snd];
      const uint4* esrc = (const uint4*)(ebuf + (size_t)grow * 32);
      const uint4* xr = (const uint4*)(xb + (size_t)rcv * 128);
      const uint4* xs = (const uint4*)(xb + (size_t)snd * 128);
      const uint4* us = (const uint4*)(ub + g * 32);
#pragma unroll
      for (int c = 0; c < 5; ++c) {
        const int cc = q * 5 + c;
        uint4 v;
        if (cc < 4)       v = esrc[cc];
        else if (cc < 20) v = xr[cc - 4];
        else if (cc < 36) v = xs[cc - 20];
        else              v = us[cc - 36];
        *(uint4*)&Asm[r][cc * 8] = v;
      }
    } else {
      const bool valid = grow < nRows;
      const uint4 zero = {0u, 0u, 0u, 0u};
      // x cols [q*16, q*16+16)
      if (valid) {
        const uint4* xs = (const uint4*)(xb + (size_t)grow * 128 + q * 16);
        *(uint4*)&Asm[r][q * 16] = xs[0];
        *(uint4*)&Asm[r][q * 16 + 8] = xs[1];
      } else {
        *(uint4*)&Asm[r][q * 16] = zero;
        *(uint4*)&Asm[r][q * 16 + 8] = zero;
      }
      // CSR gather-sum of e2, cols [128+q*16, +16)
      float4 a[4];
#pragma unroll
      for (int k = 0; k < 4; ++k) a[k] = float4{0.f, 0.f, 0.f, 0.f};
      if (valid) {
        const int start = offs[grow];
        const int deg = cnt[grow];
        int j = 0;
        for (; j + 2 <= deg; j += 2) {
          const int e0 = eidlist[start + j], e1 = eidlist[start + j + 1];
          const float4* s0 = (const float4*)(aggsrc + (size_t)e0 * 128 + q * 16);
          const float4* s1 = (const float4*)(aggsrc + (size_t)e1 * 128 + q * 16);
#pragma unroll
          for (int k = 0; k < 4; ++k) {
            float4 v0 = s0[k], v1 = s1[k];
            a[k].x += v0.x + v1.x; a[k].y += v0.y + v1.y;
            a[k].z += v0.z + v1.z; a[k].w += v0.w + v1.w;
          }
        }
        if (j < deg) {
          const int e0 = eidlist[start + j];
          const float4* s0 = (const float4*)(aggsrc + (size_t)e0 * 128 + q * 16);
#pragma unroll
          for (int k = 0; k < 4; ++k) {
            float4 v0 = s0[k];
            a[k].x += v0.x; a[k].y += v0.y; a[k].z += v0.z; a[k].w += v0.w;
          }
        }
      }
#pragma unroll
      for (int k = 0; k < 4; ++k) {
        ushort4 o;
        o.x = f2bf(a[k].x); o.y = f2bf(a[k].y);
        o.z = f2bf(a[k].z); o.w = f2bf(a[k].w);
        *(ushort4*)&Asm[r][128 + q * 16 + k * 4] = o;
      }
      // u (cols 256..287) by q<4; pad (288..319) by q>=4
      if (q < 4) {
        const int g = valid ? batch[grow] : 0;
        uint4 uv = valid ? *(const uint4*)(ub + g * 32 + q * 8) : zero;
        *(uint4*)&Asm[r][256 + q * 8] = uv;
      } else {
        *(uint4*)&Asm[r][288 + (q - 4) * 8] = zero;
      }
    }
  }
  __syncthreads();  // A staged

  // ---- GEMM1: no barriers, B from registers ----
  f32x4 acc[2][2];
#pragma unroll
  for (int mb = 0; mb < 2; ++mb)
#pragma unroll
    for (int ni = 0; ni < 2; ++ni) acc[mb][ni] = f32x4{0.f, 0.f, 0.f, 0.f};
#pragma unroll
  for (int kc = 0; kc < 5; ++kc) {
#pragma unroll
    for (int mb = 0; mb < 2; ++mb) {
      bf16x8 a0 = *(bf16x8*)&Asm[wm * 32 + mb * 16 + l15][kc * 64 + lg * 8];
      bf16x8 a1 = *(bf16x8*)&Asm[wm * 32 + mb * 16 + l15][kc * 64 + 32 + lg * 8];
#pragma unroll
      for (int ni = 0; ni < 2; ++ni) {
        acc[mb][ni] = MFMA16(a0, B1[ni][kc][0], acc[mb][ni]);
        acc[mb][ni] = MFMA16(a1, B1[ni][kc][1], acc[mb][ni]);
      }
    }
  }

  // ---- B2 registers (8 frags, 32 VGPR) ----
  bf16x8 B2[2][2][2];
  {
    const unsigned short* w2b = W2T + (size_t)(wn * 32 + l15) * 128 + lg * 8;
#pragma unroll
    for (int ni = 0; ni < 2; ++ni)
#pragma unroll
      for (int kc = 0; kc < 2; ++kc)
#pragma unroll
        for (int h = 0; h < 2; ++h)
          B2[ni][kc][h] =
              *(const bf16x8*)(w2b + ni * (16 * 128) + kc * 64 + h * 32);
  }

  if (MODE == 1) __syncthreads();  // Asm reads done before alias writes

  // ---- h1 = relu(C1 + b1) -> Hsm; MODE1: zero bins ----
#pragma unroll
  for (int mb = 0; mb < 2; ++mb)
#pragma unroll
    for (int ni = 0; ni < 2; ++ni) {
      const int ncol = wn * 32 + ni * 16 + l15;
      const float bias = cb1[ncol];
#pragma unroll
      for (int reg = 0; reg < 4; ++reg)
        Hsm[wm * 32 + mb * 16 + lg * 4 + reg][ncol] =
            f2bf(fmaxf(acc[mb][ni][reg] + bias, 0.f));
    }
  if (MODE == 1) {
    for (int i = tid; i < NG * 128; i += 512) bins[i] = 0.f;
  }
  __syncthreads();  // Hsm complete

  // ---- GEMM2 ----
  f32x4 acc2[2][2];
#pragma unroll
  for (int mb = 0; mb < 2; ++mb)
#pragma unroll
    for (int ni = 0; ni < 2; ++ni) acc2[mb][ni] = f32x4{0.f, 0.f, 0.f, 0.f};
#pragma unroll
  for (int kc = 0; kc < 2; ++kc) {
#pragma unroll
    for (int mb = 0; mb < 2; ++mb) {
      bf16x8 a0 = *(bf16x8*)&Hsm[wm * 32 + mb * 16 + l15][kc * 64 + lg * 8];
      bf16x8 a1 = *(bf16x8*)&Hsm[wm * 32 + mb * 16 + l15][kc * 64 + 32 + lg * 8];
#pragma unroll
      for (int ni = 0; ni < 2; ++ni) {
        acc2[mb][ni] = MFMA16(a0, B2[ni][kc][0], acc2[mb][ni]);
        acc2[mb][ni] = MFMA16(a1, B2[ni][kc][1], acc2[mb][ni]);
      }
    }
  }

  // ---- epilogue: bias+relu, cross-wave LN partials ----
  float hv[2][2][4];
  float sr[2][4], ssr[2][4];
#pragma unroll
  for (int mb = 0; mb < 2; ++mb)
#pragma unroll
    for (int reg = 0; reg < 4; ++reg) { sr[mb][reg] = 0.f; ssr[mb][reg] = 0.f; }
#pragma unroll
  for (int mb = 0; mb < 2; ++mb)
#pragma unroll
    for (int ni = 0; ni < 2; ++ni) {
      const int ncol = wn * 32 + ni * 16 + l15;
      const float bias = cb2[ncol];
#pragma unroll
      for (int reg = 0; reg < 4; ++reg) {
        const float h = fmaxf(acc2[mb][ni][reg] + bias, 0.f);
        hv[mb][ni][reg] = h;
        sr[mb][reg] += h; ssr[mb][reg] += h * h;
      }
    }
#pragma unroll
  for (int mb = 0; mb < 2; ++mb)
#pragma unroll
    for (int reg = 0; reg < 4; ++reg) {
      float s = sr[mb][reg], ss = ssr[mb][reg];
#pragma unroll
      for (int off = 1; off < 16; off <<= 1) {
        s += __shfl_xor(s, off, 64);
        ss += __shfl_xor(ss, off, 64);
      }
      sr[mb][reg] = s; ssr[mb][reg] = ss;
    }
  if (l15 == 0) {
#pragma unroll
    for (int mb = 0; mb < 2; ++mb)
#pragma unroll
      for (int reg = 0; reg < 4; ++reg) {
        const int r = wm * 32 + mb * 16 + lg * 4 + reg;
        ps[r][wn] = sr[mb][reg];
        pss[r][wn] = ssr[mb][reg];
      }
  }
  __syncthreads();  // partials ready

  // ---- normalize + store (+ MODE1 bins) ----
#pragma unroll
  for (int mb = 0; mb < 2; ++mb)
#pragma unroll
    for (int reg = 0; reg < 4; ++reg) {
      const int r = wm * 32 + mb * 16 + lg * 4 + reg;
      const int grow = blockIdx.x * 64 + r;
      if (MODE == 1 && grow >= nRows) continue;
      const float S = ps[r][0] + ps[r][1] + ps[r][2] + ps[r][3];
      const float SS = pss[r][0] + pss[r][1] + pss[r][2] + pss[r][3];
      const float mu = S * (1.f / 128.f);
      const float var = SS * (1.f / 128.f) - mu * mu;
      const float rstd = rsqrtf(var + EPSV);
      int g = 0;
      if (MODE == 1) g = batch[grow];
#pragma unroll
      for (int ni = 0; ni < 2; ++ni) {
        const int ncol = wn * 32 + ni * 16 + l15;
        const float y = cg[ncol] * (hv[mb][ni][reg] - mu) * rstd + cbt[ncol];
        out[(size_t)grow * 128 + ncol] = y;
        if (MODE == 1) atomicAdd(&bins[g * 128 + ncol], y);
      }
    }
  if (MODE == 1) {
    __syncthreads();
    const int first = blockIdx.x * 64;
    const int last = min(first + 63, nRows - 1);
    const int gmin = batch[first], gmax = batch[last];
    const int cntf = (gmax - gmin + 1) * 128;
    for (int i = tid; i < cntf; i += 512)
      atomicAdd(&aggout[gmin * 128 + i], bins[gmin * 128 + i]);
  }
}

// ---- edge->global: sender-sorted streaming reduce, register accumulation ----
__global__ __launch_bounds__(256) void seg_sorted_kernel(
    const float* __restrict__ data, const int* __restrict__ eidl,
    const int* __restrict__ gs, float* __restrict__ e2g) {
  const int t = threadIdx.x;
  const int col = t & 127, sub = t >> 7;
  const int start = blockIdx.x * 800;   // 1000 blocks x 800 positions
  int gcur = gs[start + sub];
  float acc = 0.f;
  for (int it = 0; it < 50; ++it) {
    const int base = start + sub + it * 16;
    int eid[8], g[8];
#pragma unroll
    for (int j = 0; j < 8; ++j) {
      eid[j] = eidl[base + j * 2];
      g[j]   = gs[base + j * 2];
    }
    float v[8];
#pragma unroll
    for (int j = 0; j < 8; ++j)
      v[j] = data[(size_t)eid[j] * 128 + col];
#pragma unroll
    for (int j = 0; j < 8; ++j) {
      if (g[j] != gcur) {
        atomicAdd(&e2g[gcur * 128 + col], acc);
        gcur = g[j]; acc = 0.f;
      }
      acc += v[j];
    }
  }
  atomicAdd(&e2g[gcur * 128 + col], acc);
}

// ---------------- global MLP (tiny) ----------------
__global__ __launch_bounds__(128) void glob_kernel(
    const float* __restrict__ u, const float* __restrict__ n2g,
    const float* __restrict__ e2g,
    const float* __restrict__ gW1, const float* __restrict__ gb1,
    const float* __restrict__ gW2, const float* __restrict__ gb2,
    const float* __restrict__ gg, const float* __restrict__ gbt,
    float* __restrict__ outU) {
  __shared__ float in[288];
  __shared__ float h1[128];
  __shared__ float red[4];
  const int g = blockIdx.x, t = threadIdx.x;
  if (t < 32) in[t] = u[g * 32 + t];
  in[32 + t] = n2g[g * 128 + t];
  in[160 + t] = e2g[g * 128 + t];
  __syncthreads();
  float a = gb1[t];
  for (int k = 0; k < 288; ++k) a += in[k] * gW1[k * 128 + t];
  h1[t] = fmaxf(a, 0.f);
  __syncthreads();
  float h = gb2[t];
  for (int k = 0; k < 128; ++k) h += h1[k] * gW2[k * 128 + t];
  h = fmaxf(h, 0.f);
  float s = h, ss = h * h;
  for (int off = 1; off < 64; off <<= 1) {
    s += __shfl_xor(s, off, 64);
    ss += __shfl_xor(ss, off, 64);
  }
  if ((t & 63) == 0) { red[(t >> 6) * 2] = s; red[(t >> 6) * 2 + 1] = ss; }
  __syncthreads();
  const float S = red[0] + red[2], SS = red[1] + red[3];
  const float mu = S * (1.f / 128.f);
  const float var = SS * (1.f / 128.f) - mu * mu;
  const float rstd = rsqrtf(var + EPSV);
  outU[g * 128 + t] = gg[t] * (h - mu) * rstd + gbt[t];
}

// ---------------- launch ----------------
extern "C" void kernel_launch(void* const* d_in, const int* in_sizes, int n_in,
                              void* d_out, int out_size, void* d_ws,
                              size_t ws_size, hipStream_t stream) {
  const float* x   = (const float*)d_in[0];
  const float* e   = (const float*)d_in[1];
  const float* u   = (const float*)d_in[2];
  const int* eidx  = (const int*)d_in[3];
  const int* batch = (const int*)d_in[4];
  const float* eW1 = (const float*)d_in[5];
  const float* eb1 = (const float*)d_in[6];
  const float* eW2 = (const float*)d_in[7];
  const float* eb2 = (const float*)d_in[8];
  const float* eg  = (const float*)d_in[9];
  const float* ebt = (const float*)d_in[10];
  const float* nW1 = (const float*)d_in[11];
  const float* nb1 = (const float*)d_in[12];
  const float* nW2 = (const float*)d_in[13];
  const float* nb2 = (const float*)d_in[14];
  const float* ng  = (const float*)d_in[15];
  const float* nbt = (const float*)d_in[16];
  const float* gW1 = (const float*)d_in[17];
  const float* gb1 = (const float*)d_in[18];
  const float* gW2 = (const float*)d_in[19];
  const float* gb2 = (const float*)d_in[20];
  const float* gg  = (const float*)d_in[21];
  const float* gbt = (const float*)d_in[22];

  char* ws = (char*)d_ws;
  float* e2g           = (float*)(ws + 0);          //    32,768
  float* n2g           = (float*)(ws + 32768);      //    32,768
  int*   cnt_r         = (int*)  (ws + 65536);      //   200,000
  int*   cnt_s         = (int*)  (ws + 265536);     //   200,000
  int*   offs_r        = (int*)  (ws + 465536);     //   200,000
  int*   cur_r         = (int*)  (ws + 665536);     //   200,000
  int*   offs_s        = (int*)  (ws + 865536);     //   200,000
  int*   cur_s         = (int*)  (ws + 1065536);    //   200,000
  int*   eidlist_r     = (int*)  (ws + 1265536);    // 3,200,000
  int*   eidlist_s     = (int*)  (ws + 4465536);    // 3,200,000
  int*   gs            = (int*)  (ws + 7665536);    // 3,200,000
  unsigned short* xb   = (unsigned short*)(ws + 10865536);  // 12,800,000
  unsigned short* eb   = (unsigned short*)(ws + 23665536);  // 51,200,000
  unsigned short* ub   = (unsigned short*)(ws + 74865536);  //     4,096
  unsigned short* eW1T = (unsigned short*)(ws + 74869632);  //    81,920
  unsigned short* eW2T = (unsigned short*)(ws + 74951552);  //    32,768
  unsigned short* nW1T = (unsigned short*)(ws + 74984320);  //    81,920
  unsigned short* nW2T = (unsigned short*)(ws + 75066240);  //    32,768
  // total ws use: ~75.1 MB

  // zero e2g + n2g + cnt_r + cnt_s (contiguous)
  hipMemsetAsync(ws, 0, 465536, stream);

  cvt_vec_kernel<<<2048, 256, 0, stream>>>(x, e, xb, eb);
  cvt_small_kernel<<<456, 256, 0, stream>>>(u, eW1, eW2, nW1, nW2, ub, eW1T,
                                            eW2T, nW1T, nW2T);

  float* outX = (float*)d_out;                 // [50000][128]
  float* outE = outX + (size_t)NN * 128;       // [800000][128]
  float* outU = outE + (size_t)NE * 128;       // [64][128]

  const int* rowI = eidx;        // senders
  const int* colI = eidx + NE;   // receivers

  pre_kernel<<<(NE + 255) / 256, 256, 0, stream>>>(rowI, colI, cnt_r, cnt_s);
  scan_kernel<<<1, 1024, 0, stream>>>(cnt_r, offs_r, cur_r);
  scan_kernel<<<1, 1024, 0, stream>>>(cnt_s, offs_s, cur_s);
  fill_kernel<<<(NE + 255) / 256, 256, 0, stream>>>(colI, cur_r, eidlist_r);
  fill2_kernel<<<(NE + 255) / 256, 256, 0, stream>>>(rowI, batch, cur_s,
                                                     eidlist_s, gs);

  mlp_kernel<0><<<NE / 64, 512, 0, stream>>>(
      eb, xb, ub, nullptr, rowI, colI, batch, nullptr, nullptr, nullptr,
      eW1T, eW2T, eb1, eb2, eg, ebt, outE, nullptr, NE);
  seg_sorted_kernel<<<1000, 256, 0, stream>>>(outE, eidlist_s, gs, e2g);
  mlp_kernel<1><<<(NN + 63) / 64, 512, 0, stream>>>(
      nullptr, xb, ub, outE, nullptr, nullptr, batch, offs_r, cnt_r, eidlist_r,
      nW1T, nW2T, nb1, nb2, ng, nbt, outX, n2g, NN);
  glob_kernel<<<NG, 128, 0, stream>>>(u, n2g, e2g, gW1, gb1, gW2, gb2, gg, gbt,
                                      outU);
}

// Round 8
// 998.155 us; speedup vs baseline: 1.1791x; 1.1791x over previous
//
#include <hip/hip_runtime.h>
#include <hip/hip_bf16.h>

typedef __attribute__((ext_vector_type(8))) short bf16x8;
typedef __attribute__((ext_vector_type(4))) float f32x4;

#define EPSV 1e-5f
#define NN 50000
#define NE 800000
#define NG 64
#define MFMA16(a, b, c) __builtin_amdgcn_mfma_f32_16x16x32_bf16(a, b, c, 0, 0, 0)

__device__ __forceinline__ unsigned short f2bf(float f) {
  union { float f; unsigned u; } v; v.f = f;
  unsigned r = v.u + 0x7FFFu + ((v.u >> 16) & 1u);
  return (unsigned short)(r >> 16);
}
__device__ __forceinline__ float bf2f(unsigned short h) {
  union { unsigned u; float f; } v; v.u = ((unsigned)h) << 16;
  return v.f;
}

// ---------------- conversion kernels ----------------

__global__ __launch_bounds__(256) void cvt_vec_kernel(
    const float* __restrict__ x, const float* __restrict__ e,
    unsigned short* __restrict__ xb, unsigned short* __restrict__ eb) {
  const int NX4 = (NN * 128) / 4;
  const int NE4 = (NE * 32) / 4;
  const int total = NX4 + NE4;
  for (int idx = blockIdx.x * 256 + threadIdx.x; idx < total;
       idx += gridDim.x * 256) {
    float4 v = (idx < NX4) ? ((const float4*)x)[idx]
                           : ((const float4*)e)[idx - NX4];
    ushort4 o;
    o.x = f2bf(v.x); o.y = f2bf(v.y); o.z = f2bf(v.z); o.w = f2bf(v.w);
    if (idx < NX4) ((ushort4*)xb)[idx] = o;
    else           ((ushort4*)eb)[idx - NX4] = o;
  }
}

// weight transposes: W1eT[128][32], WpqT[256][128], eW2T[128][128],
// nW1T[128][320], nW2T[128][128], ub
__global__ __launch_bounds__(256) void cvt_small_kernel(
    const float* __restrict__ u,
    const float* __restrict__ eW1, const float* __restrict__ eW2,
    const float* __restrict__ nW1, const float* __restrict__ nW2,
    unsigned short* __restrict__ ub,
    unsigned short* __restrict__ W1eT, unsigned short* __restrict__ WpqT,
    unsigned short* __restrict__ eW2T,
    unsigned short* __restrict__ nW1T, unsigned short* __restrict__ nW2T) {
  int i = blockIdx.x * 256 + threadIdx.x;
  const int R0 = NG * 32;           // 2048
  const int R1 = R0 + 128 * 32;     // +4096  W1eT
  const int R2 = R1 + 256 * 128;    // +32768 WpqT
  const int R3 = R2 + 128 * 128;    // +16384 eW2T
  const int R4 = R3 + 128 * 320;    // +40960 nW1T
  const int R5 = R4 + 128 * 128;    // +16384 nW2T
  if (i < R0) {
    ub[i] = f2bf(u[i]);
  } else if (i < R1) {
    int j = i - R0; int n = j >> 5, k = j & 31;
    W1eT[j] = f2bf(eW1[k * 128 + n]);
  } else if (i < R2) {
    int j = i - R1; int n = j >> 7, k = j & 127;
    WpqT[j] = (n < 128) ? f2bf(eW1[(32 + k) * 128 + n])
                        : f2bf(eW1[(160 + k) * 128 + (n - 128)]);
  } else if (i < R3) {
    int j = i - R2; int n = j >> 7, k = j & 127;
    eW2T[j] = f2bf(eW2[k * 128 + n]);
  } else if (i < R4) {
    int j = i - R3; int n = j / 320, k = j % 320;
    nW1T[j] = (k < 288) ? f2bf(nW1[k * 128 + n]) : (unsigned short)0;
  } else if (i < R5) {
    int j = i - R4; int n = j >> 7, k = j & 127;
    nW2T[j] = f2bf(nW2[k * 128 + n]);
  }
}

// R[g][n] = sum_k u[g][k] * eW1[288+k][n]  (f32, tiny)
__global__ __launch_bounds__(128) void rg_kernel(
    const float* __restrict__ u, const float* __restrict__ eW1,
    float* __restrict__ R) {
  const int g = blockIdx.x, n = threadIdx.x;
  float s = 0.f;
#pragma unroll
  for (int k = 0; k < 32; ++k) s += u[g * 32 + k] * eW1[(288 + k) * 128 + n];
  R[g * 128 + n] = s;
}

// ---------------- PQ precompute: PQ[50000][256] = Xb @ [W1r | W1s] ----------------
__global__ __launch_bounds__(256, 2) void pq_kernel(
    const unsigned short* __restrict__ xb,
    const unsigned short* __restrict__ WpqT,  // [256][128]
    unsigned short* __restrict__ PQ) {
  __shared__ __align__(16) unsigned short Asm[64][136];
  __shared__ __align__(16) unsigned short Bsm[256][72];
  const int tid = threadIdx.x;
  {
    const int r = tid >> 2, q = tid & 3;
    const int grow = blockIdx.x * 64 + r;
    const uint4 zero = {0u, 0u, 0u, 0u};
    if (grow < NN) {
      const uint4* xs = (const uint4*)(xb + (size_t)grow * 128 + q * 32);
#pragma unroll
      for (int k = 0; k < 4; ++k) *(uint4*)&Asm[r][q * 32 + k * 8] = xs[k];
    } else {
#pragma unroll
      for (int k = 0; k < 4; ++k) *(uint4*)&Asm[r][q * 32 + k * 8] = zero;
    }
  }
  const int w = tid >> 6, lane = tid & 63;
  const int l15 = lane & 15, lg = lane >> 4;
  f32x4 acc[16];
#pragma unroll
  for (int ni = 0; ni < 16; ++ni) acc[ni] = f32x4{0.f, 0.f, 0.f, 0.f};
  for (int kc = 0; kc < 2; ++kc) {
    {
      const uint4* src = (const uint4*)(WpqT + (size_t)tid * 128 + kc * 64);
#pragma unroll
      for (int k = 0; k < 8; ++k) *(uint4*)&Bsm[tid][k * 8] = src[k];
    }
    __syncthreads();
    bf16x8 a0 = *(bf16x8*)&Asm[w * 16 + l15][kc * 64 + lg * 8];
    bf16x8 a1 = *(bf16x8*)&Asm[w * 16 + l15][kc * 64 + 32 + lg * 8];
#pragma unroll
    for (int ni = 0; ni < 16; ++ni) {
      bf16x8 b0 = *(bf16x8*)&Bsm[ni * 16 + l15][lg * 8];
      bf16x8 b1 = *(bf16x8*)&Bsm[ni * 16 + l15][32 + lg * 8];
      acc[ni] = MFMA16(a0, b0, acc[ni]);
      acc[ni] = MFMA16(a1, b1, acc[ni]);
    }
    __syncthreads();
  }
  // funnel through LDS (alias Bsm, dead) for vectorized writes
  unsigned short (*Cl)[264] = (unsigned short(*)[264])&Bsm[0][0];  // 33.8KB<=36.9
#pragma unroll
  for (int ni = 0; ni < 16; ++ni)
#pragma unroll
    for (int reg = 0; reg < 4; ++reg)
      Cl[w * 16 + lg * 4 + reg][l15 + ni * 16] = f2bf(acc[ni][reg]);
  __syncthreads();
  {
    const int r = tid >> 2, q = tid & 3;
    const int grow = blockIdx.x * 64 + r;
    if (grow < NN) {
#pragma unroll
      for (int k = 0; k < 8; ++k)
        *(uint4*)(PQ + (size_t)grow * 256 + q * 64 + k * 8) =
            *(uint4*)&Cl[r][q * 64 + k * 8];
    }
  }
}

// ---------------- CSR construction (receiver + sender) ----------------

__global__ __launch_bounds__(256) void pre_kernel(
    const int* __restrict__ rowIdx, const int* __restrict__ colIdx,
    int* __restrict__ cnt_r, int* __restrict__ cnt_s) {
  int i = blockIdx.x * 256 + threadIdx.x;
  if (i < NE) {
    atomicAdd(&cnt_r[colIdx[i]], 1);
    atomicAdd(&cnt_s[rowIdx[i]], 1);
  }
}

__global__ __launch_bounds__(1024) void scan_kernel(
    const int* __restrict__ cnt, int* __restrict__ offs,
    int* __restrict__ cur) {
  __shared__ int sums[1024];
  const int t = threadIdx.x;
  const int base = t * 49;
  int s = 0;
  for (int j = 0; j < 49; ++j) {
    int idx = base + j;
    if (idx < NN) s += cnt[idx];
  }
  sums[t] = s;
  __syncthreads();
  for (int off = 1; off < 1024; off <<= 1) {
    int add = (t >= off) ? sums[t - off] : 0;
    __syncthreads();
    sums[t] += add;
    __syncthreads();
  }
  int run = (t == 0) ? 0 : sums[t - 1];
  for (int j = 0; j < 49; ++j) {
    int idx = base + j;
    if (idx < NN) {
      offs[idx] = run; cur[idx] = run;
      run += cnt[idx];
    }
  }
}

__global__ __launch_bounds__(256) void fill_kernel(
    const int* __restrict__ colIdx, int* __restrict__ cur,
    int* __restrict__ eidlist) {
  int i = blockIdx.x * 256 + threadIdx.x;
  if (i < NE) {
    int p = atomicAdd(&cur[colIdx[i]], 1);
    eidlist[p] = i;
  }
}

__global__ __launch_bounds__(256) void fill2_kernel(
    const int* __restrict__ rowIdx, const int* __restrict__ batch,
    int* __restrict__ cur_s, int* __restrict__ eidlist_s,
    int* __restrict__ gs) {
  int i = blockIdx.x * 256 + threadIdx.x;
  if (i < NE) {
    const int r = rowIdx[i];
    const int p = atomicAdd(&cur_s[r], 1);
    eidlist_s[p] = i;
    gs[p] = batch[r];
  }
}

// ---------------- edge MLP: GEMM1 decomposed via PQ/R precompute ----------------
// 64 rows/block, 256 thr = 4 waves; wave w owns rows w*16..+15, all 128 cols.
// h1 = relu(e@W1e (one MFMA) + P[rcv] + Q[snd] + R[g] + b1); GEMM2 LDS-staged.
__global__ __launch_bounds__(256, 2) void edge_kernel(
    const unsigned short* __restrict__ eb,
    const unsigned short* __restrict__ PQ,   // [NN][256] bf16: [P|Q]
    const float* __restrict__ R,             // [NG][128] f32
    const int* __restrict__ rowI, const int* __restrict__ colI,
    const int* __restrict__ batch,
    const unsigned short* __restrict__ W1eT, // [128][32]
    const unsigned short* __restrict__ W2T,  // [128][128]
    const float* __restrict__ b1, const float* __restrict__ b2,
    const float* __restrict__ gam, const float* __restrict__ bet,
    float* __restrict__ outE) {
  __shared__ __align__(16) unsigned short B1e[128][40];
  __shared__ __align__(16) unsigned short Ssm[64][136];
  __shared__ __align__(16) unsigned short Hsm[64][136];
  __shared__ __align__(16) unsigned short Bsm[128][72];
  __shared__ float cb1[128], cb2[128], cg[128], cbt[128];

  const int tid = threadIdx.x;
  if (tid < 128) {
    cb1[tid] = b1[tid]; cb2[tid] = b2[tid];
    cg[tid] = gam[tid]; cbt[tid] = bet[tid];
    const uint4* s = (const uint4*)(W1eT + tid * 32);
#pragma unroll
    for (int k = 0; k < 4; ++k) *(uint4*)&B1e[tid][k * 8] = s[k];
  }

  // ---- stage S = P[rcv] + Q[snd] + R[g] (bf16): 4 thr/row, 32 cols each ----
  {
    const int r = tid >> 2, q = tid & 3;
    const int grow = blockIdx.x * 64 + r;
    const int rcv = colI[grow];
    const int snd = rowI[grow];
    const int g = batch[snd];
    const unsigned short* pp = PQ + (size_t)rcv * 256 + q * 32;
    const unsigned short* qq = PQ + (size_t)snd * 256 + 128 + q * 32;
    const float* rr = R + g * 128 + q * 32;
#pragma unroll
    for (int k = 0; k < 8; ++k) {     // 8 groups of 4 cols
      ushort4 pv = *(const ushort4*)(pp + k * 4);
      ushort4 qv = *(const ushort4*)(qq + k * 4);
      float4 rv = *(const float4*)(rr + k * 4);
      ushort4 o;
      o.x = f2bf(bf2f(pv.x) + bf2f(qv.x) + rv.x);
      o.y = f2bf(bf2f(pv.y) + bf2f(qv.y) + rv.y);
      o.z = f2bf(bf2f(pv.z) + bf2f(qv.z) + rv.z);
      o.w = f2bf(bf2f(pv.w) + bf2f(qv.w) + rv.w);
      *(ushort4*)&Ssm[r][q * 32 + k * 4] = o;
    }
  }
  __syncthreads();

  const int w = tid >> 6, lane = tid & 63;
  const int l15 = lane & 15, lg = lane >> 4;

  // ---- GEMM1: C1 = e @ W1e, K=32 -> ONE MFMA per ni; A direct from global ----
  f32x4 acc[8];
#pragma unroll
  for (int ni = 0; ni < 8; ++ni) acc[ni] = f32x4{0.f, 0.f, 0.f, 0.f};
  {
    bf16x8 a = *(const bf16x8*)(eb + (size_t)(blockIdx.x * 64 + w * 16 + l15) * 32 + lg * 8);
#pragma unroll
    for (int ni = 0; ni < 8; ++ni) {
      bf16x8 b0 = *(bf16x8*)&B1e[ni * 16 + l15][lg * 8];
      acc[ni] = MFMA16(a, b0, acc[ni]);
    }
  }

  // ---- h1 = relu(C1 + S + b1) -> Hsm ----
#pragma unroll
  for (int ni = 0; ni < 8; ++ni) {
    const int ncol = l15 + ni * 16;
    const float bias = cb1[ncol];
#pragma unroll
    for (int reg = 0; reg < 4; ++reg) {
      const int mrow = w * 16 + lg * 4 + reg;
      const float sv = bf2f(Ssm[mrow][ncol]);
      Hsm[mrow][ncol] = f2bf(fmaxf(acc[ni][reg] + sv + bias, 0.f));
    }
  }
  __syncthreads();

  // ---- GEMM2: C2 = H1 @ W2, 2 LDS-staged K-chunks ----
  f32x4 acc2[8];
#pragma unroll
  for (int ni = 0; ni < 8; ++ni) acc2[ni] = f32x4{0.f, 0.f, 0.f, 0.f};
  for (int kc = 0; kc < 2; ++kc) {
    {
      const int n = tid >> 1, half = tid & 1;
      const uint4* src = (const uint4*)(W2T + (size_t)n * 128 + kc * 64 + half * 32);
#pragma unroll
      for (int k = 0; k < 4; ++k)
        *(uint4*)&Bsm[n][half * 32 + k * 8] = src[k];
    }
    __syncthreads();
    bf16x8 a0 = *(bf16x8*)&Hsm[w * 16 + l15][kc * 64 + lg * 8];
    bf16x8 a1 = *(bf16x8*)&Hsm[w * 16 + l15][kc * 64 + 32 + lg * 8];
#pragma unroll
    for (int ni = 0; ni < 8; ++ni) {
      bf16x8 b0 = *(bf16x8*)&Bsm[ni * 16 + l15][lg * 8];
      bf16x8 b1 = *(bf16x8*)&Bsm[ni * 16 + l15][32 + lg * 8];
      acc2[ni] = MFMA16(a0, b0, acc2[ni]);
      acc2[ni] = MFMA16(a1, b1, acc2[ni]);
    }
    __syncthreads();
  }

  // ---- epilogue: bias + relu + LayerNorm (intra-wave) + store ----
  float hv[8][4];
  float sreg[4] = {0.f, 0.f, 0.f, 0.f}, ssreg[4] = {0.f, 0.f, 0.f, 0.f};
#pragma unroll
  for (int ni = 0; ni < 8; ++ni) {
    const int ncol = l15 + ni * 16;
    const float bias = cb2[ncol];
#pragma unroll
    for (int reg = 0; reg < 4; ++reg) {
      const float h = fmaxf(acc2[ni][reg] + bias, 0.f);
      hv[ni][reg] = h;
      sreg[reg] += h; ssreg[reg] += h * h;
    }
  }
#pragma unroll
  for (int reg = 0; reg < 4; ++reg) {
    float s = sreg[reg], ss = ssreg[reg];
#pragma unroll
    for (int off = 1; off < 16; off <<= 1) {
      s += __shfl_xor(s, off, 64);
      ss += __shfl_xor(ss, off, 64);
    }
    sreg[reg] = s; ssreg[reg] = ss;
  }
#pragma unroll
  for (int reg = 0; reg < 4; ++reg) {
    const int grow = blockIdx.x * 64 + w * 16 + lg * 4 + reg;
    const float mu = sreg[reg] * (1.f / 128.f);
    const float var = ssreg[reg] * (1.f / 128.f) - mu * mu;
    const float rstd = rsqrtf(var + EPSV);
#pragma unroll
    for (int ni = 0; ni < 8; ++ni) {
      const int ncol = l15 + ni * 16;
      const float y = cg[ncol] * (hv[ni][reg] - mu) * rstd + cbt[ncol];
      outE[(size_t)grow * 128 + ncol] = y;
    }
  }
}

// ---------------- node MLP (round-6 known-good, MODE=1 only) ----------------
template <int MODE>
__global__ __launch_bounds__(256, 2) void mlp_kernel(
    const unsigned short* __restrict__ ebuf,
    const unsigned short* __restrict__ xb,
    const unsigned short* __restrict__ ub,
    const float* __restrict__ aggsrc,
    const int* __restrict__ rowIdx, const int* __restrict__ colIdx,
    const int* __restrict__ batch,
    const int* __restrict__ offs, const int* __restrict__ cnt,
    const int* __restrict__ eidlist,
    const unsigned short* __restrict__ W1T,
    const unsigned short* __restrict__ W2T,
    const float* __restrict__ b1, const float* __restrict__ b2,
    const float* __restrict__ gam, const float* __restrict__ bet,
    float* __restrict__ out, float* __restrict__ aggout, int nRows) {
  constexpr int USZ = (MODE == 1) ? 50176 : 41984;
  __shared__ __align__(16) char U[USZ];
  __shared__ __align__(16) unsigned short Bsm[128][72];
  __shared__ float cb1[128], cb2[128], cg[128], cbt[128];
  unsigned short (*Asm)[328] = (unsigned short(*)[328])U;
  unsigned short (*Hsm)[136] = (unsigned short(*)[136])U;
  float* bins = (float*)(U + 17408);

  const int tid = threadIdx.x;
  if (tid < 128) {
    cb1[tid] = b1[tid]; cb2[tid] = b2[tid];
    cg[tid] = gam[tid]; cbt[tid] = bet[tid];
  }

  {
    const int r = tid >> 2, q = tid & 3;
    const int grow = blockIdx.x * 64 + r;
    if (MODE == 0) {
      // unused in this build
    } else {
      const bool valid = grow < nRows;
      const uint4 zero = {0u, 0u, 0u, 0u};
      if (valid) {
        const uint4* xs = (const uint4*)(xb + (size_t)grow * 128 + q * 32);
#pragma unroll
        for (int k = 0; k < 4; ++k) *(uint4*)&Asm[r][q * 32 + k * 8] = xs[k];
      } else {
#pragma unroll
        for (int k = 0; k < 4; ++k) *(uint4*)&Asm[r][q * 32 + k * 8] = zero;
      }
      float4 a[8];
#pragma unroll
      for (int k = 0; k < 8; ++k) a[k] = float4{0.f, 0.f, 0.f, 0.f};
      if (valid) {
        const int start = offs[grow];
        const int deg = cnt[grow];
        int j = 0;
        for (; j + 2 <= deg; j += 2) {
          const int e0 = eidlist[start + j], e1 = eidlist[start + j + 1];
          const float4* s0 = (const float4*)(aggsrc + (size_t)e0 * 128 + q * 32);
          const float4* s1 = (const float4*)(aggsrc + (size_t)e1 * 128 + q * 32);
#pragma unroll
          for (int k = 0; k < 8; ++k) {
            float4 v0 = s0[k], v1 = s1[k];
            a[k].x += v0.x + v1.x; a[k].y += v0.y + v1.y;
            a[k].z += v0.z + v1.z; a[k].w += v0.w + v1.w;
          }
        }
        if (j < deg) {
          const int e0 = eidlist[start + j];
          const float4* s0 = (const float4*)(aggsrc + (size_t)e0 * 128 + q * 32);
#pragma unroll
          for (int k = 0; k < 8; ++k) {
            float4 v0 = s0[k];
            a[k].x += v0.x; a[k].y += v0.y; a[k].z += v0.z; a[k].w += v0.w;
          }
        }
      }
#pragma unroll
      for (int k = 0; k < 8; ++k) {
        ushort4 o;
        o.x = f2bf(a[k].x); o.y = f2bf(a[k].y);
        o.z = f2bf(a[k].z); o.w = f2bf(a[k].w);
        *(ushort4*)&Asm[r][128 + q * 32 + k * 4] = o;
      }
      const int g = valid ? batch[grow] : 0;
      uint4 uv = valid ? *(const uint4*)(ub + g * 32 + q * 8) : zero;
      *(uint4*)&Asm[r][256 + q * 8] = uv;
      *(uint4*)&Asm[r][288 + q * 8] = zero;
    }
  }

  const int w = tid >> 6;
  const int lane = tid & 63;
  const int l15 = lane & 15, lg = lane >> 4;

  f32x4 acc[8];
#pragma unroll
  for (int ni = 0; ni < 8; ++ni) acc[ni] = f32x4{0.f, 0.f, 0.f, 0.f};

  for (int kc = 0; kc < 5; ++kc) {
    {
      const int n = tid >> 1, half = tid & 1;
      const uint4* src = (const uint4*)(W1T + (size_t)n * 320 + kc * 64 + half * 32);
#pragma unroll
      for (int k = 0; k < 4; ++k)
        *(uint4*)&Bsm[n][half * 32 + k * 8] = src[k];
    }
    __syncthreads();
    bf16x8 a0 = *(bf16x8*)&Asm[w * 16 + l15][kc * 64 + lg * 8];
    bf16x8 a1 = *(bf16x8*)&Asm[w * 16 + l15][kc * 64 + 32 + lg * 8];
#pragma unroll
    for (int ni = 0; ni < 8; ++ni) {
      bf16x8 bb0 = *(bf16x8*)&Bsm[ni * 16 + l15][lg * 8];
      bf16x8 bb1 = *(bf16x8*)&Bsm[ni * 16 + l15][32 + lg * 8];
      acc[ni] = MFMA16(a0, bb0, acc[ni]);
      acc[ni] = MFMA16(a1, bb1, acc[ni]);
    }
    __syncthreads();
  }

#pragma unroll
  for (int ni = 0; ni < 8; ++ni) {
    const int ncol = l15 + ni * 16;
    const float bias = cb1[ncol];
#pragma unroll
    for (int reg = 0; reg < 4; ++reg) {
      const int mrow = w * 16 + lg * 4 + reg;
      Hsm[mrow][ncol] = f2bf(fmaxf(acc[ni][reg] + bias, 0.f));
    }
  }
  if (MODE == 1) {
    for (int i = tid; i < NG * 128; i += 256) bins[i] = 0.f;
  }

  f32x4 acc2[8];
#pragma unroll
  for (int ni = 0; ni < 8; ++ni) acc2[ni] = f32x4{0.f, 0.f, 0.f, 0.f};
  for (int kc = 0; kc < 2; ++kc) {
    {
      const int n = tid >> 1, half = tid & 1;
      const uint4* src = (const uint4*)(W2T + (size_t)n * 128 + kc * 64 + half * 32);
#pragma unroll
      for (int k = 0; k < 4; ++k)
        *(uint4*)&Bsm[n][half * 32 + k * 8] = src[k];
    }
    __syncthreads();
    bf16x8 a0 = *(bf16x8*)&Hsm[w * 16 + l15][kc * 64 + lg * 8];
    bf16x8 a1 = *(bf16x8*)&Hsm[w * 16 + l15][kc * 64 + 32 + lg * 8];
#pragma unroll
    for (int ni = 0; ni < 8; ++ni) {
      bf16x8 bb0 = *(bf16x8*)&Bsm[ni * 16 + l15][lg * 8];
      bf16x8 bb1 = *(bf16x8*)&Bsm[ni * 16 + l15][32 + lg * 8];
      acc2[ni] = MFMA16(a0, bb0, acc2[ni]);
      acc2[ni] = MFMA16(a1, bb1, acc2[ni]);
    }
    __syncthreads();
  }

  float hv[8][4];
  float sreg[4] = {0.f, 0.f, 0.f, 0.f}, ssreg[4] = {0.f, 0.f, 0.f, 0.f};
#pragma unroll
  for (int ni = 0; ni < 8; ++ni) {
    const int ncol = l15 + ni * 16;
    const float bias = cb2[ncol];
#pragma unroll
    for (int reg = 0; reg < 4; ++reg) {
      const float h = fmaxf(acc2[ni][reg] + bias, 0.f);
      hv[ni][reg] = h;
      sreg[reg] += h; ssreg[reg] += h * h;
    }
  }
#pragma unroll
  for (int reg = 0; reg < 4; ++reg) {
    float s = sreg[reg], ss = ssreg[reg];
#pragma unroll
    for (int off = 1; off < 16; off <<= 1) {
      s += __shfl_xor(s, off, 64);
      ss += __shfl_xor(ss, off, 64);
    }
    sreg[reg] = s; ssreg[reg] = ss;
  }
#pragma unroll
  for (int reg = 0; reg < 4; ++reg) {
    const int mrow = w * 16 + lg * 4 + reg;
    const int grow = blockIdx.x * 64 + mrow;
    if (MODE == 1 && grow >= nRows) continue;
    const float mu = sreg[reg] * (1.f / 128.f);
    const float var = ssreg[reg] * (1.f / 128.f) - mu * mu;
    const float rstd = rsqrtf(var + EPSV);
    int g = 0;
    if (MODE == 1) g = batch[grow];
#pragma unroll
    for (int ni = 0; ni < 8; ++ni) {
      const int ncol = l15 + ni * 16;
      const float y = cg[ncol] * (hv[ni][reg] - mu) * rstd + cbt[ncol];
      out[(size_t)grow * 128 + ncol] = y;
      if (MODE == 1) atomicAdd(&bins[g * 128 + ncol], y);
    }
  }
  if (MODE == 1) {
    __syncthreads();
    const int first = blockIdx.x * 64;
    const int last = min(first + 63, nRows - 1);
    const int gmin = batch[first], gmax = batch[last];
    const int cntf = (gmax - gmin + 1) * 128;
    for (int i = tid; i < cntf; i += 256)
      atomicAdd(&aggout[gmin * 128 + i], bins[gmin * 128 + i]);
  }
}

// ---- edge->global: sender-sorted streaming reduce ----
__global__ __launch_bounds__(256) void seg_sorted_kernel(
    const float* __restrict__ data, const int* __restrict__ eidl,
    const int* __restrict__ gs, float* __restrict__ e2g) {
  const int t = threadIdx.x;
  const int col = t & 127, sub = t >> 7;
  const int start = blockIdx.x * 800;
  int gcur = gs[start + sub];
  float acc = 0.f;
  for (int it = 0; it < 50; ++it) {
    const int base = start + sub + it * 16;
    int eid[8], g[8];
#pragma unroll
    for (int j = 0; j < 8; ++j) {
      eid[j] = eidl[base + j * 2];
      g[j]   = gs[base + j * 2];
    }
    float v[8];
#pragma unroll
    for (int j = 0; j < 8; ++j)
      v[j] = data[(size_t)eid[j] * 128 + col];
#pragma unroll
    for (int j = 0; j < 8; ++j) {
      if (g[j] != gcur) {
        atomicAdd(&e2g[gcur * 128 + col], acc);
        gcur = g[j]; acc = 0.f;
      }
      acc += v[j];
    }
  }
  atomicAdd(&e2g[gcur * 128 + col], acc);
}

// ---------------- global MLP (tiny) ----------------
__global__ __launch_bounds__(128) void glob_kernel(
    const float* __restrict__ u, const float* __restrict__ n2g,
    const float* __restrict__ e2g,
    const float* __restrict__ gW1, const float* __restrict__ gb1,
    const float* __restrict__ gW2, const float* __restrict__ gb2,
    const float* __restrict__ gg, const float* __restrict__ gbt,
    float* __restrict__ outU) {
  __shared__ float in[288];
  __shared__ float h1[128];
  __shared__ float red[4];
  const int g = blockIdx.x, t = threadIdx.x;
  if (t < 32) in[t] = u[g * 32 + t];
  in[32 + t] = n2g[g * 128 + t];
  in[160 + t] = e2g[g * 128 + t];
  __syncthreads();
  float a = gb1[t];
  for (int k = 0; k < 288; ++k) a += in[k] * gW1[k * 128 + t];
  h1[t] = fmaxf(a, 0.f);
  __syncthreads();
  float h = gb2[t];
  for (int k = 0; k < 128; ++k) h += h1[k] * gW2[k * 128 + t];
  h = fmaxf(h, 0.f);
  float s = h, ss = h * h;
  for (int off = 1; off < 64; off <<= 1) {
    s += __shfl_xor(s, off, 64);
    ss += __shfl_xor(ss, off, 64);
  }
  if ((t & 63) == 0) { red[(t >> 6) * 2] = s; red[(t >> 6) * 2 + 1] = ss; }
  __syncthreads();
  const float S = red[0] + red[2], SS = red[1] + red[3];
  const float mu = S * (1.f / 128.f);
  const float var = SS * (1.f / 128.f) - mu * mu;
  const float rstd = rsqrtf(var + EPSV);
  outU[g * 128 + t] = gg[t] * (h - mu) * rstd + gbt[t];
}

// ---------------- launch ----------------
extern "C" void kernel_launch(void* const* d_in, const int* in_sizes, int n_in,
                              void* d_out, int out_size, void* d_ws,
                              size_t ws_size, hipStream_t stream) {
  const float* x   = (const float*)d_in[0];
  const float* e   = (const float*)d_in[1];
  const float* u   = (const float*)d_in[2];
  const int* eidx  = (const int*)d_in[3];
  const int* batch = (const int*)d_in[4];
  const float* eW1 = (const float*)d_in[5];
  const float* eb1 = (const float*)d_in[6];
  const float* eW2 = (const float*)d_in[7];
  const float* eb2 = (const float*)d_in[8];
  const float* eg  = (const float*)d_in[9];
  const float* ebt = (const float*)d_in[10];
  const float* nW1 = (const float*)d_in[11];
  const float* nb1 = (const float*)d_in[12];
  const float* nW2 = (const float*)d_in[13];
  const float* nb2 = (const float*)d_in[14];
  const float* ng  = (const float*)d_in[15];
  const float* nbt = (const float*)d_in[16];
  const float* gW1 = (const float*)d_in[17];
  const float* gb1 = (const float*)d_in[18];
  const float* gW2 = (const float*)d_in[19];
  const float* gb2 = (const float*)d_in[20];
  const float* gg  = (const float*)d_in[21];
  const float* gbt = (const float*)d_in[22];

  char* ws = (char*)d_ws;
  float* e2g           = (float*)(ws + 0);          //    32,768
  float* n2g           = (float*)(ws + 32768);      //    32,768
  int*   cnt_r         = (int*)  (ws + 65536);      //   200,000
  int*   cnt_s         = (int*)  (ws + 265536);     //   200,000
  int*   offs_r        = (int*)  (ws + 465536);     //   200,000
  int*   cur_r         = (int*)  (ws + 665536);     //   200,000
  int*   offs_s        = (int*)  (ws + 865536);     //   200,000
  int*   cur_s         = (int*)  (ws + 1065536);    //   200,000
  int*   eidlist_r     = (int*)  (ws + 1265536);    // 3,200,000
  int*   eidlist_s     = (int*)  (ws + 4465536);    // 3,200,000
  int*   gs            = (int*)  (ws + 7665536);    // 3,200,000
  unsigned short* xb   = (unsigned short*)(ws + 10865536);  // 12,800,000
  unsigned short* eb   = (unsigned short*)(ws + 23665536);  // 51,200,000
  unsigned short* ub   = (unsigned short*)(ws + 74865536);  //     4,096
  unsigned short* W1eT = (unsigned short*)(ws + 74869632);  //     8,192
  unsigned short* WpqT = (unsigned short*)(ws + 74877824);  //    65,536
  unsigned short* eW2T = (unsigned short*)(ws + 74943360);  //    32,768
  unsigned short* nW1T = (unsigned short*)(ws + 74976128);  //    81,920
  unsigned short* nW2T = (unsigned short*)(ws + 75058048);  //    32,768
  unsigned short* PQ   = (unsigned short*)(ws + 75090816);  // 25,600,000
  float* Rg            = (float*)(ws + 100690816);          //    32,768
  // total ws use: ~100.7 MB

  hipMemsetAsync(ws, 0, 465536, stream);

  cvt_vec_kernel<<<2048, 256, 0, stream>>>(x, e, xb, eb);
  cvt_small_kernel<<<440, 256, 0, stream>>>(u, eW1, eW2, nW1, nW2, ub, W1eT,
                                            WpqT, eW2T, nW1T, nW2T);
  rg_kernel<<<NG, 128, 0, stream>>>(u, eW1, Rg);
  pq_kernel<<<(NN + 63) / 64, 256, 0, stream>>>(xb, WpqT, PQ);

  float* outX = (float*)d_out;                 // [50000][128]
  float* outE = outX + (size_t)NN * 128;       // [800000][128]
  float* outU = outE + (size_t)NE * 128;       // [64][128]

  const int* rowI = eidx;        // senders
  const int* colI = eidx + NE;   // receivers

  pre_kernel<<<(NE + 255) / 256, 256, 0, stream>>>(rowI, colI, cnt_r, cnt_s);
  scan_kernel<<<1, 1024, 0, stream>>>(cnt_r, offs_r, cur_r);
  scan_kernel<<<1, 1024, 0, stream>>>(cnt_s, offs_s, cur_s);
  fill_kernel<<<(NE + 255) / 256, 256, 0, stream>>>(colI, cur_r, eidlist_r);
  fill2_kernel<<<(NE + 255) / 256, 256, 0, stream>>>(rowI, batch, cur_s,
                                                     eidlist_s, gs);

  edge_kernel<<<NE / 64, 256, 0, stream>>>(eb, PQ, Rg, rowI, colI, batch,
                                           W1eT, eW2T, eb1, eb2, eg, ebt, outE);
  seg_sorted_kernel<<<1000, 256, 0, stream>>>(outE, eidlist_s, gs, e2g);
  mlp_kernel<1><<<(NN + 63) / 64, 256, 0, stream>>>(
      nullptr, xb, ub, outE, nullptr, nullptr, batch, offs_r, cnt_r, eidlist_r,
      nW1T, nW2T, nb1, nb2, ng, nbt, outX, n2g, NN);
  glob_kernel<<<NG, 128, 0, stream>>>(u, n2g, e2g, gW1, gb1, gW2, gb2, gg, gbt,
                                      outU);
}